// Round 1
// baseline (214.199 us; speedup 1.0000x reference)
//
#include <hip/hip_runtime.h>
#include <hip/hip_bf16.h>

#define T_TOK 2048
#define DMODEL 1024
#define HEXP 512
#define NEXP 16
#define TOPK 4
#define CAP 2048

typedef __attribute__((ext_vector_type(4))) float f32x4;
typedef __attribute__((ext_vector_type(8))) short short8;   // 8 bf16 (4 VGPRs) MFMA operand
typedef __attribute__((ext_vector_type(4))) unsigned short ush4;
typedef __attribute__((ext_vector_type(8))) unsigned short ush8;

static __device__ __forceinline__ unsigned short f2bf(float f) {
  union { float f; unsigned int u; } v; v.f = f;
  unsigned int r = v.u + 0x7FFFu + ((v.u >> 16) & 1u);
  return (unsigned short)(r >> 16);
}

// ---------------- transpose + cast: in [E][R][C] f32 -> out [E][C][R] bf16 ----------------
__global__ __launch_bounds__(256) void tcast(const float* __restrict__ in,
                                             unsigned short* __restrict__ out,
                                             int R, int C) {
  __shared__ unsigned short lds[64][68];  // +4 pad keeps 8B alignment (stride 136B)
  int e = blockIdx.z;
  in  += (size_t)e * R * C;
  out += (size_t)e * R * C;
  int r0 = blockIdx.x * 64, c0 = blockIdx.y * 64;
  int tid = (int)threadIdx.x;
  int rr = tid >> 4;             // 0..15
  int cc = (tid & 15) * 4;       // 0..60
#pragma unroll
  for (int i = 0; i < 4; i++) {
    int row = rr + i * 16;
    f32x4 v = *(const f32x4*)(in + (size_t)(r0 + row) * C + c0 + cc);
    ush4 b = { f2bf(v[0]), f2bf(v[1]), f2bf(v[2]), f2bf(v[3]) };
    *(ush4*)&lds[row][cc] = b;
  }
  __syncthreads();
#pragma unroll
  for (int j = 0; j < 4; j++) {
    int orow = rr + j * 16;
    ush4 b = { lds[cc + 0][orow], lds[cc + 1][orow], lds[cc + 2][orow], lds[cc + 3][orow] };
    *(ush4*)(out + (size_t)(c0 + orow) * R + r0 + cc) = b;
  }
}

// ---------------- router: fp32 logits, sigmoid, top-4, build expert lists, cast x->bf16 ----
__global__ __launch_bounds__(64) void router(const float* __restrict__ x,
                                             const float* __restrict__ cen,
                                             const float* __restrict__ bias,
                                             unsigned short* __restrict__ xbf,
                                             int* __restrict__ cnt,
                                             int* __restrict__ listTok,
                                             float* __restrict__ listGate,
                                             int* __restrict__ listSlot) {
  int t = blockIdx.x, lane = (int)threadIdx.x;
  const float* xr = x + (size_t)t * DMODEL;
  f32x4 xv[4];
#pragma unroll
  for (int i = 0; i < 4; i++) xv[i] = *(const f32x4*)(xr + i * 256 + lane * 4);
  // cast row to bf16
  unsigned short* xb = xbf + (size_t)t * DMODEL;
#pragma unroll
  for (int i = 0; i < 4; i++) {
    ush4 b = { f2bf(xv[i][0]), f2bf(xv[i][1]), f2bf(xv[i][2]), f2bf(xv[i][3]) };
    *(ush4*)(xb + i * 256 + lane * 4) = b;
  }
  // 16 logits, full-wave dot products
  float myscore = -1e30f;
  for (int e = 0; e < NEXP; e++) {
    const float* ce = cen + (size_t)e * DMODEL;
    float p = 0.f;
#pragma unroll
    for (int i = 0; i < 4; i++) {
      f32x4 cv = *(const f32x4*)(ce + i * 256 + lane * 4);
#pragma unroll
      for (int j = 0; j < 4; j++) p = fmaf(xv[i][j], cv[j], p);
    }
#pragma unroll
    for (int o = 32; o >= 1; o >>= 1) p += __shfl_xor(p, o);
    if (lane == e) {
      float z = p + bias[e];
      myscore = 1.f / (1.f + expf(-z));
    }
  }
  // top-4 (lowest index wins ties, matching jax.lax.top_k)
  int sel[4]; float val[4]; float gsum = 0.f;
  bool taken = false;
#pragma unroll
  for (int k = 0; k < 4; k++) {
    float cv2 = taken ? -1e30f : myscore;
    float m = cv2;
#pragma unroll
    for (int o = 32; o >= 1; o >>= 1) m = fmaxf(m, __shfl_xor(m, o));
    unsigned long long msk = __ballot(cv2 == m);
    int win = __ffsll(msk) - 1;
    if (lane == win) taken = true;
    sel[k] = win; val[k] = m; gsum += m;
  }
  gsum = fmaxf(gsum, 1e-9f);
#pragma unroll
  for (int k = 0; k < 4; k++) {
    if (lane == k) {
      int e = sel[k];
      int pos = atomicAdd(&cnt[e], 1);
      listTok[e * CAP + pos] = t;
      listGate[e * CAP + pos] = val[k] / gsum;
      listSlot[e * CAP + pos] = t * 4 + k;
    }
  }
}

// ---------------- FFN part 1: h = silu(x@wg) * (x@wu) * gate, gathered rows --------------
__global__ __launch_bounds__(256) void ffn1(const unsigned short* __restrict__ xbf,
                                            const unsigned short* __restrict__ wgT,
                                            const unsigned short* __restrict__ wuT,
                                            const int* __restrict__ cnt,
                                            const int* __restrict__ listTok,
                                            const float* __restrict__ listGate,
                                            unsigned short* __restrict__ hbuf) {
  int e = blockIdx.z;
  int c = cnt[e];
  int m0 = blockIdx.y * 64;
  if (m0 >= c) return;
  int n0 = blockIdx.x * 64;
  __shared__ unsigned short sA[64][72];
  __shared__ unsigned short sG[64][72];
  __shared__ unsigned short sU[64][72];
  __shared__ int sTok[64];
  __shared__ float sGate[64];
  int tid = (int)threadIdx.x;
  if (tid < 64) {
    int r = m0 + tid;
    sTok[tid]  = (r < c) ? listTok[e * CAP + r] : listTok[e * CAP];
    sGate[tid] = (r < c) ? listGate[e * CAP + r] : 0.f;
  }
  __syncthreads();
  int lane = tid & 63, wid = tid >> 6;
  int wr = wid >> 1, wc = wid & 1;
  const unsigned short* wg = wgT + ((size_t)e * HEXP + n0) * DMODEL;
  const unsigned short* wu = wuT + ((size_t)e * HEXP + n0) * DMODEL;
  f32x4 ag[2][2] = {{{0,0,0,0},{0,0,0,0}},{{0,0,0,0},{0,0,0,0}}};
  f32x4 au[2][2] = {{{0,0,0,0},{0,0,0,0}},{{0,0,0,0},{0,0,0,0}}};
  int ldr = tid >> 3;            // 0..31
  int ldc = (tid & 7) << 3;      // 0..56
  for (int k0 = 0; k0 < DMODEL; k0 += 64) {
    __syncthreads();
#pragma unroll
    for (int v = 0; v < 2; v++) {
      int row = ldr + v * 32;
      *(ush8*)&sA[row][ldc] = *(const ush8*)(xbf + (size_t)sTok[row] * DMODEL + k0 + ldc);
      *(ush8*)&sG[row][ldc] = *(const ush8*)(wg + (size_t)row * DMODEL + k0 + ldc);
      *(ush8*)&sU[row][ldc] = *(const ush8*)(wu + (size_t)row * DMODEL + k0 + ldc);
    }
    __syncthreads();
#pragma unroll
    for (int kk = 0; kk < 2; kk++) {
      int kb = (kk << 5) + ((lane >> 4) << 3);
      int ra = (wr << 5) + (lane & 15);
      int rb = (wc << 5) + (lane & 15);
      short8 a0 = *(const short8*)&sA[ra][kb];
      short8 a1 = *(const short8*)&sA[ra + 16][kb];
      short8 g0 = *(const short8*)&sG[rb][kb];
      short8 g1 = *(const short8*)&sG[rb + 16][kb];
      short8 u0 = *(const short8*)&sU[rb][kb];
      short8 u1 = *(const short8*)&sU[rb + 16][kb];
      ag[0][0] = __builtin_amdgcn_mfma_f32_16x16x32_bf16(a0, g0, ag[0][0], 0, 0, 0);
      ag[0][1] = __builtin_amdgcn_mfma_f32_16x16x32_bf16(a0, g1, ag[0][1], 0, 0, 0);
      ag[1][0] = __builtin_amdgcn_mfma_f32_16x16x32_bf16(a1, g0, ag[1][0], 0, 0, 0);
      ag[1][1] = __builtin_amdgcn_mfma_f32_16x16x32_bf16(a1, g1, ag[1][1], 0, 0, 0);
      au[0][0] = __builtin_amdgcn_mfma_f32_16x16x32_bf16(a0, u0, au[0][0], 0, 0, 0);
      au[0][1] = __builtin_amdgcn_mfma_f32_16x16x32_bf16(a0, u1, au[0][1], 0, 0, 0);
      au[1][0] = __builtin_amdgcn_mfma_f32_16x16x32_bf16(a1, u0, au[1][0], 0, 0, 0);
      au[1][1] = __builtin_amdgcn_mfma_f32_16x16x32_bf16(a1, u1, au[1][1], 0, 0, 0);
    }
  }
  int rlo = (lane >> 4) << 2;
  int cl = lane & 15;
#pragma unroll
  for (int mi = 0; mi < 2; mi++) {
#pragma unroll
    for (int r = 0; r < 4; r++) {
      int row = (wr << 5) + mi * 16 + rlo + r;
      int grow = m0 + row;
      if (grow < c) {
        float gwt = sGate[row];
#pragma unroll
        for (int ni = 0; ni < 2; ni++) {
          int col = n0 + (wc << 5) + ni * 16 + cl;
          float g = ag[mi][ni][r];
          float u = au[mi][ni][r];
          float sig = 1.f / (1.f + __expf(-g));
          float h = g * sig * u * gwt;
          hbuf[((size_t)e * CAP + grow) * HEXP + col] = f2bf(h);
        }
      }
    }
  }
}

// ---------------- FFN part 2: y[slot] = h @ w_down  (per-(token,k) fp32 partials) ---------
__global__ __launch_bounds__(256) void ffn2(const unsigned short* __restrict__ hbuf,
                                            const unsigned short* __restrict__ wdT,
                                            const int* __restrict__ cnt,
                                            const int* __restrict__ listSlot,
                                            float* __restrict__ y) {
  int e = blockIdx.z;
  int c = cnt[e];
  int m0 = blockIdx.y * 64;
  if (m0 >= c) return;
  int n0 = blockIdx.x * 64;
  __shared__ unsigned short sA[64][72];
  __shared__ unsigned short sB[64][72];
  __shared__ int sSlot[64];
  int tid = (int)threadIdx.x;
  if (tid < 64) {
    int r = m0 + tid;
    sSlot[tid] = (r < c) ? listSlot[e * CAP + r] : 0;
  }
  __syncthreads();
  int lane = tid & 63, wid = tid >> 6;
  int wr = wid >> 1, wc = wid & 1;
  const unsigned short* ha = hbuf + ((size_t)e * CAP + m0) * HEXP;
  const unsigned short* wd = wdT + ((size_t)e * DMODEL + n0) * HEXP;
  f32x4 acc[2][2] = {{{0,0,0,0},{0,0,0,0}},{{0,0,0,0},{0,0,0,0}}};
  int ldr = tid >> 3, ldc = (tid & 7) << 3;
  for (int k0 = 0; k0 < HEXP; k0 += 64) {
    __syncthreads();
#pragma unroll
    for (int v = 0; v < 2; v++) {
      int row = ldr + v * 32;
      *(ush8*)&sA[row][ldc] = *(const ush8*)(ha + (size_t)row * HEXP + k0 + ldc);
      *(ush8*)&sB[row][ldc] = *(const ush8*)(wd + (size_t)row * HEXP + k0 + ldc);
    }
    __syncthreads();
#pragma unroll
    for (int kk = 0; kk < 2; kk++) {
      int kb = (kk << 5) + ((lane >> 4) << 3);
      int ra = (wr << 5) + (lane & 15);
      int rb = (wc << 5) + (lane & 15);
      short8 a0 = *(const short8*)&sA[ra][kb];
      short8 a1 = *(const short8*)&sA[ra + 16][kb];
      short8 b0 = *(const short8*)&sB[rb][kb];
      short8 b1 = *(const short8*)&sB[rb + 16][kb];
      acc[0][0] = __builtin_amdgcn_mfma_f32_16x16x32_bf16(a0, b0, acc[0][0], 0, 0, 0);
      acc[0][1] = __builtin_amdgcn_mfma_f32_16x16x32_bf16(a0, b1, acc[0][1], 0, 0, 0);
      acc[1][0] = __builtin_amdgcn_mfma_f32_16x16x32_bf16(a1, b0, acc[1][0], 0, 0, 0);
      acc[1][1] = __builtin_amdgcn_mfma_f32_16x16x32_bf16(a1, b1, acc[1][1], 0, 0, 0);
    }
  }
  int rlo = (lane >> 4) << 2;
  int cl = lane & 15;
#pragma unroll
  for (int mi = 0; mi < 2; mi++) {
#pragma unroll
    for (int r = 0; r < 4; r++) {
      int row = (wr << 5) + mi * 16 + rlo + r;
      int grow = m0 + row;
      if (grow < c) {
        int slot = sSlot[row];
#pragma unroll
        for (int ni = 0; ni < 2; ni++) {
          int col = n0 + (wc << 5) + ni * 16 + cl;
          y[(size_t)slot * DMODEL + col] = acc[mi][ni][r];
        }
      }
    }
  }
}

// ---------------- final reduce over the 4 expert slots + scale ---------------------------
__global__ __launch_bounds__(256) void reducek(const float* __restrict__ y,
                                               const float* __restrict__ scale,
                                               float* __restrict__ out) {
  int i = blockIdx.x * 256 + (int)threadIdx.x;  // 524288 total, 4 floats each
  int t = i >> 8;
  int d = (i & 255) << 2;
  const float* yb = y + (size_t)t * 4 * DMODEL + d;
  f32x4 s = *(const f32x4*)(yb);
  s += *(const f32x4*)(yb + DMODEL);
  s += *(const f32x4*)(yb + 2 * DMODEL);
  s += *(const f32x4*)(yb + 3 * DMODEL);
  float sc = scale[0];
  s *= sc;
  *(f32x4*)(out + (size_t)t * DMODEL + d) = s;
}

extern "C" void kernel_launch(void* const* d_in, const int* in_sizes, int n_in,
                              void* d_out, int out_size, void* d_ws, size_t ws_size,
                              hipStream_t stream) {
  const float* x      = (const float*)d_in[0];
  const float* cen    = (const float*)d_in[1];
  const float* bias   = (const float*)d_in[2];
  const float* w_gate = (const float*)d_in[3];
  const float* w_up   = (const float*)d_in[4];
  const float* w_down = (const float*)d_in[5];
  const float* scale  = (const float*)d_in[6];
  float* out = (float*)d_out;

  char* ws = (char*)d_ws;
  // workspace layout (needs ~116.4 MB)
  unsigned short* xbf  = (unsigned short*)(ws);                 //  4 MB
  unsigned short* wgT  = (unsigned short*)(ws + 4194304);       // 16 MB  [E][H][D] bf16
  unsigned short* wuT  = (unsigned short*)(ws + 20971520);      // 16 MB
  unsigned short* wdT  = (unsigned short*)(ws + 37748736);      // 16 MB  [E][D][H] bf16
  unsigned short* hbuf = (unsigned short*)(ws + 54525952);      // 32 MB  [E][CAP][H] bf16
  float*          y    = (float*)(ws + 88080384);               // 32 MB  [T*4][D] f32
  int*            cnt  = (int*)(ws + 121634816);
  int*        listTok  = (int*)(ws + 121635072);
  float*     listGate  = (float*)(ws + 121766144);
  int*       listSlot  = (int*)(ws + 121897216);

  hipMemsetAsync(cnt, 0, 64, stream);
  tcast<<<dim3(16, 8, 16), 256, 0, stream>>>(w_gate, wgT, 1024, 512);
  tcast<<<dim3(16, 8, 16), 256, 0, stream>>>(w_up,   wuT, 1024, 512);
  tcast<<<dim3(8, 16, 16), 256, 0, stream>>>(w_down, wdT, 512, 1024);
  router<<<dim3(2048), 64, 0, stream>>>(x, cen, bias, xbf, cnt, listTok, listGate, listSlot);
  ffn1<<<dim3(8, 32, 16), 256, 0, stream>>>(xbf, wgT, wuT, cnt, listTok, listGate, hbuf);
  ffn2<<<dim3(16, 32, 16), 256, 0, stream>>>(hbuf, wdT, cnt, listSlot, y);
  reducek<<<dim3(2048), 256, 0, stream>>>(y, scale, out);
}

// Round 4
// 211.798 us; speedup vs baseline: 1.0113x; 1.0113x over previous
//
#include <hip/hip_runtime.h>
#include <hip/hip_bf16.h>

#define T_TOK 2048
#define DMODEL 1024
#define HEXP 512
#define NEXP 16
#define TOPK 4
#define CAP 2048

typedef __attribute__((ext_vector_type(4))) float f32x4;
typedef __attribute__((ext_vector_type(8))) short short8;   // 8 bf16 (4 VGPRs) MFMA operand
typedef __attribute__((ext_vector_type(4))) unsigned short ush4;
typedef __attribute__((ext_vector_type(8))) unsigned short ush8;

static __device__ __forceinline__ unsigned short f2bf(float f) {
  union { float f; unsigned int u; } v; v.f = f;
  unsigned int r = v.u + 0x7FFFu + ((v.u >> 16) & 1u);
  return (unsigned short)(r >> 16);
}

// ---------------- transpose + cast: in [E][R][C] f32 -> out [E][C][R] bf16 ----------------
__global__ __launch_bounds__(256) void tcast(const float* __restrict__ in,
                                             unsigned short* __restrict__ out,
                                             int R, int C) {
  __shared__ unsigned short lds[64][68];  // +4 pad keeps 8B alignment (stride 136B)
  int e = blockIdx.z;
  in  += (size_t)e * R * C;
  out += (size_t)e * R * C;
  int r0 = blockIdx.x * 64, c0 = blockIdx.y * 64;
  int tid = (int)threadIdx.x;
  int rr = tid >> 4;             // 0..15
  int cc = (tid & 15) * 4;       // 0..60
#pragma unroll
  for (int i = 0; i < 4; i++) {
    int row = rr + i * 16;
    f32x4 v = *(const f32x4*)(in + (size_t)(r0 + row) * C + c0 + cc);
    ush4 b = { f2bf(v[0]), f2bf(v[1]), f2bf(v[2]), f2bf(v[3]) };
    *(ush4*)&lds[row][cc] = b;
  }
  __syncthreads();
#pragma unroll
  for (int j = 0; j < 4; j++) {
    int orow = rr + j * 16;
    ush4 b = { lds[cc + 0][orow], lds[cc + 1][orow], lds[cc + 2][orow], lds[cc + 3][orow] };
    *(ush4*)(out + (size_t)(c0 + orow) * R + r0 + cc) = b;
  }
}

// ---------------- router: fp32 logits (register-accumulated), batched butterfly, ----------
// ---------------- in-register top-4, expert list build, x->bf16 cast ----------------------
__global__ __launch_bounds__(256) void router(const float* __restrict__ x,
                                              const float* __restrict__ cen,
                                              const float* __restrict__ bias,
                                              unsigned short* __restrict__ xbf,
                                              int* __restrict__ cnt,
                                              int* __restrict__ listTok,
                                              float* __restrict__ listGate,
                                              int* __restrict__ listSlot) {
  int tid = (int)threadIdx.x;
  int lane = tid & 63, wid = tid >> 6;
  int t = blockIdx.x * 4 + wid;
  const float* xr = x + (size_t)t * DMODEL;
  f32x4 xv[4];
#pragma unroll
  for (int i = 0; i < 4; i++) xv[i] = *(const f32x4*)(xr + i * 256 + lane * 4);
  // cast row to bf16
  unsigned short* xb = xbf + (size_t)t * DMODEL;
#pragma unroll
  for (int i = 0; i < 4; i++) {
    ush4 b = { f2bf(xv[i][0]), f2bf(xv[i][1]), f2bf(xv[i][2]), f2bf(xv[i][3]) };
    *(ush4*)(xb + i * 256 + lane * 4) = b;
  }
  // 16 expert partial dots accumulated in registers (independent -> full ILP)
  float p[16];
#pragma unroll
  for (int e = 0; e < NEXP; e++) p[e] = 0.f;
#pragma unroll
  for (int e = 0; e < NEXP; e++) {
    const float* ce = cen + (size_t)e * DMODEL;
#pragma unroll
    for (int i = 0; i < 4; i++) {
      f32x4 cv = *(const f32x4*)(ce + i * 256 + lane * 4);
#pragma unroll
      for (int j = 0; j < 4; j++) p[e] = fmaf(xv[i][j], cv[j], p[e]);
    }
  }
  // batched butterfly: 6 steps x 16 independent shuffles; all lanes get all 16 logits
#pragma unroll
  for (int o = 32; o >= 1; o >>= 1) {
#pragma unroll
    for (int e = 0; e < NEXP; e++) p[e] += __shfl_xor(p[e], o);
  }
  float s[16];
#pragma unroll
  for (int e = 0; e < NEXP; e++) s[e] = 1.f / (1.f + expf(-(p[e] + bias[e])));
  // in-register top-4; strictly-greater compare keeps lowest index on ties (lax.top_k)
  int sel[4]; float val[4]; float gsum = 0.f;
#pragma unroll
  for (int k = 0; k < 4; k++) {
    float best = -1e30f; int bi = 0;
#pragma unroll
    for (int e = 0; e < NEXP; e++) {
      if (s[e] > best) { best = s[e]; bi = e; }
    }
    sel[k] = bi; val[k] = best; gsum += best;
#pragma unroll
    for (int e = 0; e < NEXP; e++) if (e == bi) s[e] = -1e30f;
  }
  gsum = fmaxf(gsum, 1e-9f);
#pragma unroll
  for (int k = 0; k < 4; k++) {
    if (lane == k) {
      int e = sel[k];
      int pos = atomicAdd(&cnt[e], 1);
      listTok[e * CAP + pos] = t;
      listGate[e * CAP + pos] = val[k] / gsum;
      listSlot[e * CAP + pos] = t * 4 + k;
    }
  }
}

// ---------------- FFN part 1: h = silu(x@wg) * (x@wu) * gate, gathered rows --------------
__global__ __launch_bounds__(256) void ffn1(const unsigned short* __restrict__ xbf,
                                            const unsigned short* __restrict__ wgT,
                                            const unsigned short* __restrict__ wuT,
                                            const int* __restrict__ cnt,
                                            const int* __restrict__ listTok,
                                            const float* __restrict__ listGate,
                                            unsigned short* __restrict__ hbuf) {
  int e = blockIdx.z;
  int c = cnt[e];
  int m0 = blockIdx.y * 64;
  if (m0 >= c) return;
  int n0 = blockIdx.x * 64;
  __shared__ unsigned short sA[64][72];
  __shared__ unsigned short sG[64][72];
  __shared__ unsigned short sU[64][72];
  __shared__ int sTok[64];
  __shared__ float sGate[64];
  int tid = (int)threadIdx.x;
  if (tid < 64) {
    int r = m0 + tid;
    sTok[tid]  = (r < c) ? listTok[e * CAP + r] : listTok[e * CAP];
    sGate[tid] = (r < c) ? listGate[e * CAP + r] : 0.f;
  }
  __syncthreads();
  int lane = tid & 63, wid = tid >> 6;
  int wr = wid >> 1, wc = wid & 1;
  const unsigned short* wg = wgT + ((size_t)e * HEXP + n0) * DMODEL;
  const unsigned short* wu = wuT + ((size_t)e * HEXP + n0) * DMODEL;
  f32x4 ag[2][2] = {{{0,0,0,0},{0,0,0,0}},{{0,0,0,0},{0,0,0,0}}};
  f32x4 au[2][2] = {{{0,0,0,0},{0,0,0,0}},{{0,0,0,0},{0,0,0,0}}};
  int ldr = tid >> 3;            // 0..31
  int ldc = (tid & 7) << 3;      // 0..56
  for (int k0 = 0; k0 < DMODEL; k0 += 64) {
    __syncthreads();
#pragma unroll
    for (int v = 0; v < 2; v++) {
      int row = ldr + v * 32;
      *(ush8*)&sA[row][ldc] = *(const ush8*)(xbf + (size_t)sTok[row] * DMODEL + k0 + ldc);
      *(ush8*)&sG[row][ldc] = *(const ush8*)(wg + (size_t)row * DMODEL + k0 + ldc);
      *(ush8*)&sU[row][ldc] = *(const ush8*)(wu + (size_t)row * DMODEL + k0 + ldc);
    }
    __syncthreads();
#pragma unroll
    for (int kk = 0; kk < 2; kk++) {
      int kb = (kk << 5) + ((lane >> 4) << 3);
      int ra = (wr << 5) + (lane & 15);
      int rb = (wc << 5) + (lane & 15);
      short8 a0 = *(const short8*)&sA[ra][kb];
      short8 a1 = *(const short8*)&sA[ra + 16][kb];
      short8 g0 = *(const short8*)&sG[rb][kb];
      short8 g1 = *(const short8*)&sG[rb + 16][kb];
      short8 u0 = *(const short8*)&sU[rb][kb];
      short8 u1 = *(const short8*)&sU[rb + 16][kb];
      ag[0][0] = __builtin_amdgcn_mfma_f32_16x16x32_bf16(a0, g0, ag[0][0], 0, 0, 0);
      ag[0][1] = __builtin_amdgcn_mfma_f32_16x16x32_bf16(a0, g1, ag[0][1], 0, 0, 0);
      ag[1][0] = __builtin_amdgcn_mfma_f32_16x16x32_bf16(a1, g0, ag[1][0], 0, 0, 0);
      ag[1][1] = __builtin_amdgcn_mfma_f32_16x16x32_bf16(a1, g1, ag[1][1], 0, 0, 0);
      au[0][0] = __builtin_amdgcn_mfma_f32_16x16x32_bf16(a0, u0, au[0][0], 0, 0, 0);
      au[0][1] = __builtin_amdgcn_mfma_f32_16x16x32_bf16(a0, u1, au[0][1], 0, 0, 0);
      au[1][0] = __builtin_amdgcn_mfma_f32_16x16x32_bf16(a1, u0, au[1][0], 0, 0, 0);
      au[1][1] = __builtin_amdgcn_mfma_f32_16x16x32_bf16(a1, u1, au[1][1], 0, 0, 0);
    }
  }
  int rlo = (lane >> 4) << 2;
  int cl = lane & 15;
#pragma unroll
  for (int mi = 0; mi < 2; mi++) {
#pragma unroll
    for (int r = 0; r < 4; r++) {
      int row = (wr << 5) + mi * 16 + rlo + r;
      int grow = m0 + row;
      if (grow < c) {
        float gwt = sGate[row];
#pragma unroll
        for (int ni = 0; ni < 2; ni++) {
          int col = n0 + (wc << 5) + ni * 16 + cl;
          float g = ag[mi][ni][r];
          float u = au[mi][ni][r];
          float sig = 1.f / (1.f + __expf(-g));
          float h = g * sig * u * gwt;
          hbuf[((size_t)e * CAP + grow) * HEXP + col] = f2bf(h);
        }
      }
    }
  }
}

// ---------------- FFN part 2: y[slot] = h @ w_down  (per-(token,k) fp32 partials) ---------
__global__ __launch_bounds__(256) void ffn2(const unsigned short* __restrict__ hbuf,
                                            const unsigned short* __restrict__ wdT,
                                            const int* __restrict__ cnt,
                                            const int* __restrict__ listSlot,
                                            float* __restrict__ y) {
  int e = blockIdx.z;
  int c = cnt[e];
  int m0 = blockIdx.y * 64;
  if (m0 >= c) return;
  int n0 = blockIdx.x * 64;
  __shared__ unsigned short sA[64][72];
  __shared__ unsigned short sB[64][72];
  __shared__ int sSlot[64];
  int tid = (int)threadIdx.x;
  if (tid < 64) {
    int r = m0 + tid;
    sSlot[tid] = (r < c) ? listSlot[e * CAP + r] : 0;
  }
  __syncthreads();
  int lane = tid & 63, wid = tid >> 6;
  int wr = wid >> 1, wc = wid & 1;
  const unsigned short* ha = hbuf + ((size_t)e * CAP + m0) * HEXP;
  const unsigned short* wd = wdT + ((size_t)e * DMODEL + n0) * HEXP;
  f32x4 acc[2][2] = {{{0,0,0,0},{0,0,0,0}},{{0,0,0,0},{0,0,0,0}}};
  int ldr = tid >> 3, ldc = (tid & 7) << 3;
  for (int k0 = 0; k0 < HEXP; k0 += 64) {
    __syncthreads();
#pragma unroll
    for (int v = 0; v < 2; v++) {
      int row = ldr + v * 32;
      *(ush8*)&sA[row][ldc] = *(const ush8*)(ha + (size_t)row * HEXP + k0 + ldc);
      *(ush8*)&sB[row][ldc] = *(const ush8*)(wd + (size_t)row * HEXP + k0 + ldc);
    }
    __syncthreads();
#pragma unroll
    for (int kk = 0; kk < 2; kk++) {
      int kb = (kk << 5) + ((lane >> 4) << 3);
      int ra = (wr << 5) + (lane & 15);
      int rb = (wc << 5) + (lane & 15);
      short8 a0 = *(const short8*)&sA[ra][kb];
      short8 a1 = *(const short8*)&sA[ra + 16][kb];
      short8 b0 = *(const short8*)&sB[rb][kb];
      short8 b1 = *(const short8*)&sB[rb + 16][kb];
      acc[0][0] = __builtin_amdgcn_mfma_f32_16x16x32_bf16(a0, b0, acc[0][0], 0, 0, 0);
      acc[0][1] = __builtin_amdgcn_mfma_f32_16x16x32_bf16(a0, b1, acc[0][1], 0, 0, 0);
      acc[1][0] = __builtin_amdgcn_mfma_f32_16x16x32_bf16(a1, b0, acc[1][0], 0, 0, 0);
      acc[1][1] = __builtin_amdgcn_mfma_f32_16x16x32_bf16(a1, b1, acc[1][1], 0, 0, 0);
    }
  }
  int rlo = (lane >> 4) << 2;
  int cl = lane & 15;
#pragma unroll
  for (int mi = 0; mi < 2; mi++) {
#pragma unroll
    for (int r = 0; r < 4; r++) {
      int row = (wr << 5) + mi * 16 + rlo + r;
      int grow = m0 + row;
      if (grow < c) {
        int slot = sSlot[row];
#pragma unroll
        for (int ni = 0; ni < 2; ni++) {
          int col = n0 + (wc << 5) + ni * 16 + cl;
          y[(size_t)slot * DMODEL + col] = acc[mi][ni][r];
        }
      }
    }
  }
}

// ---------------- final reduce over the 4 expert slots + scale ---------------------------
__global__ __launch_bounds__(256) void reducek(const float* __restrict__ y,
                                               const float* __restrict__ scale,
                                               float* __restrict__ out) {
  int i = blockIdx.x * 256 + (int)threadIdx.x;  // 524288 total, 4 floats each
  int t = i >> 8;
  int d = (i & 255) << 2;
  const float* yb = y + (size_t)t * 4 * DMODEL + d;
  f32x4 s = *(const f32x4*)(yb);
  s += *(const f32x4*)(yb + DMODEL);
  s += *(const f32x4*)(yb + 2 * DMODEL);
  s += *(const f32x4*)(yb + 3 * DMODEL);
  float sc = scale[0];
  s *= sc;
  *(f32x4*)(out + (size_t)t * DMODEL + d) = s;
}

extern "C" void kernel_launch(void* const* d_in, const int* in_sizes, int n_in,
                              void* d_out, int out_size, void* d_ws, size_t ws_size,
                              hipStream_t stream) {
  const float* x      = (const float*)d_in[0];
  const float* cen    = (const float*)d_in[1];
  const float* bias   = (const float*)d_in[2];
  const float* w_gate = (const float*)d_in[3];
  const float* w_up   = (const float*)d_in[4];
  const float* w_down = (const float*)d_in[5];
  const float* scale  = (const float*)d_in[6];
  float* out = (float*)d_out;

  char* ws = (char*)d_ws;
  // workspace layout (needs ~116.4 MB)
  unsigned short* xbf  = (unsigned short*)(ws);                 //  4 MB
  unsigned short* wgT  = (unsigned short*)(ws + 4194304);       // 16 MB  [E][H][D] bf16
  unsigned short* wuT  = (unsigned short*)(ws + 20971520);      // 16 MB
  unsigned short* wdT  = (unsigned short*)(ws + 37748736);      // 16 MB  [E][D][H] bf16
  unsigned short* hbuf = (unsigned short*)(ws + 54525952);      // 32 MB  [E][CAP][H] bf16
  float*          y    = (float*)(ws + 88080384);               // 32 MB  [T*4][D] f32
  int*            cnt  = (int*)(ws + 121634816);
  int*        listTok  = (int*)(ws + 121635072);
  float*     listGate  = (float*)(ws + 121766144);
  int*       listSlot  = (int*)(ws + 121897216);

  hipMemsetAsync(cnt, 0, 64, stream);
  tcast<<<dim3(16, 8, 16), 256, 0, stream>>>(w_gate, wgT, 1024, 512);
  tcast<<<dim3(16, 8, 16), 256, 0, stream>>>(w_up,   wuT, 1024, 512);
  tcast<<<dim3(8, 16, 16), 256, 0, stream>>>(w_down, wdT, 512, 1024);
  router<<<dim3(512), 256, 0, stream>>>(x, cen, bias, xbf, cnt, listTok, listGate, listSlot);
  ffn1<<<dim3(8, 32, 16), 256, 0, stream>>>(xbf, wgT, wuT, cnt, listTok, listGate, hbuf);
  ffn2<<<dim3(16, 32, 16), 256, 0, stream>>>(hbuf, wdT, cnt, listSlot, y);
  reducek<<<dim3(2048), 256, 0, stream>>>(y, scale, out);
}

// Round 7
// 117.317 us; speedup vs baseline: 1.8258x; 1.8053x over previous
//
#include <hip/hip_runtime.h>
#include <hip/hip_bf16.h>

#define T_TOK 2048
#define DMODEL 1024
#define HEXP 512
#define NEXP 16
#define TOPK 4
#define CAP 2048

typedef __attribute__((ext_vector_type(4))) float f32x4;
typedef __attribute__((ext_vector_type(8))) short short8;   // 8 bf16 (4 VGPRs) MFMA operand
typedef __attribute__((ext_vector_type(4))) unsigned short ush4;
typedef __attribute__((ext_vector_type(8))) unsigned short ush8;
typedef __attribute__((ext_vector_type(4))) int i32x4;

static __device__ __forceinline__ unsigned short f2bf(float f) {
  union { float f; unsigned int u; } v; v.f = f;
  unsigned int r = v.u + 0x7FFFu + ((v.u >> 16) & 1u);
  return (unsigned short)(r >> 16);
}

// async global->LDS, 16B per lane; LDS dest is wave-uniform base + lane*16
static __device__ __forceinline__ void gl16(const unsigned short* g, unsigned short* l) {
  __builtin_amdgcn_global_load_lds(
      (const __attribute__((address_space(1))) unsigned int*)g,
      (__attribute__((address_space(3))) unsigned int*)l, 16, 0, 0);
}

// physical ushort index of logical (row, elem-col kb) in a 64x64 swizzled tile
// granule = row*8 + ((kb>>3) ^ (row&7)); kb must be a multiple of 8
#define SWZ(r, kb) (((r) << 6) + ((((kb) >> 3) ^ ((r) & 7)) << 3))

// ---------------- transpose + cast: in [E][R][C] f32 -> out [E][C][R] bf16 ----------------
__global__ __launch_bounds__(256) void tcast(const float* __restrict__ in,
                                             unsigned short* __restrict__ out,
                                             int R, int C) {
  __shared__ unsigned short lds[64][68];  // +4 pad keeps 8B alignment (stride 136B)
  int e = blockIdx.z;
  in  += (size_t)e * R * C;
  out += (size_t)e * R * C;
  int r0 = blockIdx.x * 64, c0 = blockIdx.y * 64;
  int tid = (int)threadIdx.x;
  int rr = tid >> 4;             // 0..15
  int cc = (tid & 15) * 4;       // 0..60
#pragma unroll
  for (int i = 0; i < 4; i++) {
    int row = rr + i * 16;
    f32x4 v = *(const f32x4*)(in + (size_t)(r0 + row) * C + c0 + cc);
    ush4 b = { f2bf(v[0]), f2bf(v[1]), f2bf(v[2]), f2bf(v[3]) };
    *(ush4*)&lds[row][cc] = b;
  }
  __syncthreads();
#pragma unroll
  for (int j = 0; j < 4; j++) {
    int orow = rr + j * 16;
    ush4 b = { lds[cc + 0][orow], lds[cc + 1][orow], lds[cc + 2][orow], lds[cc + 3][orow] };
    *(ush4*)(out + (size_t)(c0 + orow) * R + r0 + cc) = b;
  }
}

// ---------------- router: fp32 logits, in-register top-4, NO atomics ---------------------
__global__ __launch_bounds__(256) void router(const float* __restrict__ x,
                                              const float* __restrict__ cen,
                                              const float* __restrict__ bias,
                                              unsigned short* __restrict__ xbf,
                                              int* __restrict__ selIdx,
                                              float* __restrict__ selGate) {
  int tid = (int)threadIdx.x;
  int lane = tid & 63, wid = tid >> 6;
  int t = blockIdx.x * 4 + wid;
  const float* xr = x + (size_t)t * DMODEL;
  f32x4 xv[4];
#pragma unroll
  for (int i = 0; i < 4; i++) xv[i] = *(const f32x4*)(xr + i * 256 + lane * 4);
  unsigned short* xb = xbf + (size_t)t * DMODEL;
#pragma unroll
  for (int i = 0; i < 4; i++) {
    ush4 b = { f2bf(xv[i][0]), f2bf(xv[i][1]), f2bf(xv[i][2]), f2bf(xv[i][3]) };
    *(ush4*)(xb + i * 256 + lane * 4) = b;
  }
  float p[16];
#pragma unroll
  for (int e = 0; e < NEXP; e++) p[e] = 0.f;
#pragma unroll
  for (int e = 0; e < NEXP; e++) {
    const float* ce = cen + (size_t)e * DMODEL;
#pragma unroll
    for (int i = 0; i < 4; i++) {
      f32x4 cv = *(const f32x4*)(ce + i * 256 + lane * 4);
#pragma unroll
      for (int j = 0; j < 4; j++) p[e] = fmaf(xv[i][j], cv[j], p[e]);
    }
  }
#pragma unroll
  for (int o = 32; o >= 1; o >>= 1) {
#pragma unroll
    for (int e = 0; e < NEXP; e++) p[e] += __shfl_xor(p[e], o);
  }
  float s[16];
#pragma unroll
  for (int e = 0; e < NEXP; e++) s[e] = 1.f / (1.f + expf(-(p[e] + bias[e])));
  int sel[4]; float val[4]; float gsum = 0.f;
#pragma unroll
  for (int k = 0; k < 4; k++) {
    float best = -1e30f; int bi = 0;
#pragma unroll
    for (int e = 0; e < NEXP; e++) {
      if (s[e] > best) { best = s[e]; bi = e; }
    }
    sel[k] = bi; val[k] = best; gsum += best;
#pragma unroll
    for (int e = 0; e < NEXP; e++) if (e == bi) s[e] = -1e30f;
  }
  float inv = 1.f / fmaxf(gsum, 1e-9f);
  if (lane == 0) {
    i32x4 si = { sel[0], sel[1], sel[2], sel[3] };
    f32x4 sg = { val[0] * inv, val[1] * inv, val[2] * inv, val[3] * inv };
    *(i32x4*)&selIdx[t * 4] = si;
    *(f32x4*)&selGate[t * 4] = sg;
  }
}

// ---------------- buildlists: per-expert order-preserving compaction, no atomics ----------
__global__ __launch_bounds__(256) void buildlists(const int* __restrict__ selIdx,
                                                  const float* __restrict__ selGate,
                                                  int* __restrict__ cnt,
                                                  int* __restrict__ listTok,
                                                  float* __restrict__ listGate,
                                                  int* __restrict__ listSlot) {
  int e = blockIdx.x;
  int tid = (int)threadIdx.x, lane = tid & 63, w = tid >> 6;
  int i0 = tid * 32;
  int vals[32];
#pragma unroll
  for (int j = 0; j < 8; j++)
    *(i32x4*)&vals[j * 4] = *(const i32x4*)&selIdx[i0 + j * 4];
  int mycount = 0;
#pragma unroll
  for (int j = 0; j < 32; j++) mycount += (vals[j] == e) ? 1 : 0;
  int s = mycount;
#pragma unroll
  for (int o = 1; o < 64; o <<= 1) {
    int n = __shfl_up(s, o);
    if (lane >= o) s += n;
  }
  __shared__ int wtot[4];
  if (lane == 63) wtot[w] = s;
  __syncthreads();
  int wbase = 0;
#pragma unroll
  for (int j = 0; j < 4; j++) wbase += (j < w) ? wtot[j] : 0;
  int pos = wbase + s - mycount;
#pragma unroll
  for (int j = 0; j < 32; j++) {
    if (vals[j] == e) {
      int i = i0 + j;
      listTok[e * CAP + pos]  = i >> 2;
      listGate[e * CAP + pos] = selGate[i];
      listSlot[e * CAP + pos] = i;
      pos++;
    }
  }
  if (tid == 255) cnt[e] = pos;
}

// ---------------- FFN part 1: h = silu(x@wg) * (x@wu) * gate, gathered rows --------------
// 64x64 tile; global_load_lds(16B) staging into XOR-swizzled linear LDS.
__global__ __launch_bounds__(256) void ffn1(const unsigned short* __restrict__ xbf,
                                            const unsigned short* __restrict__ wgT,
                                            const unsigned short* __restrict__ wuT,
                                            const int* __restrict__ cnt,
                                            const int* __restrict__ listTok,
                                            const float* __restrict__ listGate,
                                            unsigned short* __restrict__ hbuf) {
  int e = blockIdx.z;
  int c = cnt[e];
  int m0 = blockIdx.y * 64;
  if (m0 >= c) return;
  int n0 = blockIdx.x * 64;
  __shared__ unsigned short sA[4096];
  __shared__ unsigned short sG[4096];
  __shared__ unsigned short sU[4096];
  __shared__ int sTok[64];
  __shared__ float sGate[64];
  int tid = (int)threadIdx.x;
  if (tid < 64) {
    int r = m0 + tid;
    sTok[tid]  = (r < c) ? listTok[e * CAP + r] : listTok[e * CAP];
    sGate[tid] = (r < c) ? listGate[e * CAP + r] : 0.f;
  }
  __syncthreads();
  int lane = tid & 63, wid = tid >> 6;
  int wr = wid >> 1, wc = wid & 1;
  const unsigned short* wg = wgT + ((size_t)e * HEXP + n0) * DMODEL;
  const unsigned short* wu = wuT + ((size_t)e * HEXP + n0) * DMODEL;
  // staging geometry: wave wid fills granules [wid*128, wid*128+128) = rows [wid*16, wid*16+16)
  int rloc = lane >> 3;                 // 0..7
  int c16  = (lane & 7) ^ rloc;         // pre-swizzled logical col16
  int rowA0 = wid * 16 + rloc, rowA1 = rowA0 + 8;
  const unsigned short* pA0 = xbf + (size_t)sTok[rowA0] * DMODEL + c16 * 8;
  const unsigned short* pA1 = xbf + (size_t)sTok[rowA1] * DMODEL + c16 * 8;
  const unsigned short* pG0 = wg + (size_t)rowA0 * DMODEL + c16 * 8;
  const unsigned short* pG1 = wg + (size_t)rowA1 * DMODEL + c16 * 8;
  const unsigned short* pU0 = wu + (size_t)rowA0 * DMODEL + c16 * 8;
  const unsigned short* pU1 = wu + (size_t)rowA1 * DMODEL + c16 * 8;
  unsigned short* dA = sA + wid * 1024;   // ushort units: 2048B = 1024 ushorts
  unsigned short* dG = sG + wid * 1024;
  unsigned short* dU = sU + wid * 1024;
  f32x4 ag[2][2] = {{{0,0,0,0},{0,0,0,0}},{{0,0,0,0},{0,0,0,0}}};
  f32x4 au[2][2] = {{{0,0,0,0},{0,0,0,0}},{{0,0,0,0},{0,0,0,0}}};
  for (int k0 = 0; k0 < DMODEL; k0 += 64) {
    __syncthreads();                      // previous reads done before overwrite
    gl16(pA0 + k0, dA);
    gl16(pA1 + k0, dA + 512);
    gl16(pG0 + k0, dG);
    gl16(pG1 + k0, dG + 512);
    gl16(pU0 + k0, dU);
    gl16(pU1 + k0, dU + 512);
    __syncthreads();                      // drains vmcnt before reads
#pragma unroll
    for (int kk = 0; kk < 2; kk++) {
      int kb = (kk << 5) + ((lane >> 4) << 3);
      int ra = (wr << 5) + (lane & 15);
      int rb = (wc << 5) + (lane & 15);
      short8 a0 = *(const short8*)&sA[SWZ(ra, kb)];
      short8 a1 = *(const short8*)&sA[SWZ(ra + 16, kb)];
      short8 g0 = *(const short8*)&sG[SWZ(rb, kb)];
      short8 g1 = *(const short8*)&sG[SWZ(rb + 16, kb)];
      short8 u0 = *(const short8*)&sU[SWZ(rb, kb)];
      short8 u1 = *(const short8*)&sU[SWZ(rb + 16, kb)];
      ag[0][0] = __builtin_amdgcn_mfma_f32_16x16x32_bf16(a0, g0, ag[0][0], 0, 0, 0);
      ag[0][1] = __builtin_amdgcn_mfma_f32_16x16x32_bf16(a0, g1, ag[0][1], 0, 0, 0);
      ag[1][0] = __builtin_amdgcn_mfma_f32_16x16x32_bf16(a1, g0, ag[1][0], 0, 0, 0);
      ag[1][1] = __builtin_amdgcn_mfma_f32_16x16x32_bf16(a1, g1, ag[1][1], 0, 0, 0);
      au[0][0] = __builtin_amdgcn_mfma_f32_16x16x32_bf16(a0, u0, au[0][0], 0, 0, 0);
      au[0][1] = __builtin_amdgcn_mfma_f32_16x16x32_bf16(a0, u1, au[0][1], 0, 0, 0);
      au[1][0] = __builtin_amdgcn_mfma_f32_16x16x32_bf16(a1, u0, au[1][0], 0, 0, 0);
      au[1][1] = __builtin_amdgcn_mfma_f32_16x16x32_bf16(a1, u1, au[1][1], 0, 0, 0);
    }
  }
  int rlo = (lane >> 4) << 2;
  int cl = lane & 15;
#pragma unroll
  for (int mi = 0; mi < 2; mi++) {
#pragma unroll
    for (int r = 0; r < 4; r++) {
      int row = (wr << 5) + mi * 16 + rlo + r;
      int grow = m0 + row;
      if (grow < c) {
        float gwt = sGate[row];
#pragma unroll
        for (int ni = 0; ni < 2; ni++) {
          int col = n0 + (wc << 5) + ni * 16 + cl;
          float g = ag[mi][ni][r];
          float u = au[mi][ni][r];
          float sig = 1.f / (1.f + __expf(-g));
          float h = g * sig * u * gwt;
          hbuf[((size_t)e * CAP + grow) * HEXP + col] = f2bf(h);
        }
      }
    }
  }
}

// ---------------- FFN part 2: y[slot] = h @ w_down  (per-(token,k) fp32 partials) ---------
__global__ __launch_bounds__(256) void ffn2(const unsigned short* __restrict__ hbuf,
                                            const unsigned short* __restrict__ wdT,
                                            const int* __restrict__ cnt,
                                            const int* __restrict__ listSlot,
                                            float* __restrict__ y) {
  int e = blockIdx.z;
  int c = cnt[e];
  int m0 = blockIdx.y * 64;
  if (m0 >= c) return;
  int n0 = blockIdx.x * 64;
  __shared__ unsigned short sA[4096];
  __shared__ unsigned short sB[4096];
  __shared__ int sSlot[64];
  int tid = (int)threadIdx.x;
  if (tid < 64) {
    int r = m0 + tid;
    sSlot[tid] = (r < c) ? listSlot[e * CAP + r] : 0;
  }
  __syncthreads();
  int lane = tid & 63, wid = tid >> 6;
  int wr = wid >> 1, wc = wid & 1;
  const unsigned short* ha = hbuf + ((size_t)e * CAP + m0) * HEXP;
  const unsigned short* wd = wdT + ((size_t)e * DMODEL + n0) * HEXP;
  int rloc = lane >> 3;
  int c16  = (lane & 7) ^ rloc;
  int row0 = wid * 16 + rloc, row1 = row0 + 8;
  const unsigned short* pA0 = ha + (size_t)row0 * HEXP + c16 * 8;
  const unsigned short* pA1 = ha + (size_t)row1 * HEXP + c16 * 8;
  const unsigned short* pB0 = wd + (size_t)row0 * HEXP + c16 * 8;
  const unsigned short* pB1 = wd + (size_t)row1 * HEXP + c16 * 8;
  unsigned short* dA = sA + wid * 1024;
  unsigned short* dB = sB + wid * 1024;
  f32x4 acc[2][2] = {{{0,0,0,0},{0,0,0,0}},{{0,0,0,0},{0,0,0,0}}};
  for (int k0 = 0; k0 < HEXP; k0 += 64) {
    __syncthreads();
    gl16(pA0 + k0, dA);
    gl16(pA1 + k0, dA + 512);
    gl16(pB0 + k0, dB);
    gl16(pB1 + k0, dB + 512);
    __syncthreads();
#pragma unroll
    for (int kk = 0; kk < 2; kk++) {
      int kb = (kk << 5) + ((lane >> 4) << 3);
      int ra = (wr << 5) + (lane & 15);
      int rb = (wc << 5) + (lane & 15);
      short8 a0 = *(const short8*)&sA[SWZ(ra, kb)];
      short8 a1 = *(const short8*)&sA[SWZ(ra + 16, kb)];
      short8 b0 = *(const short8*)&sB[SWZ(rb, kb)];
      short8 b1 = *(const short8*)&sB[SWZ(rb + 16, kb)];
      acc[0][0] = __builtin_amdgcn_mfma_f32_16x16x32_bf16(a0, b0, acc[0][0], 0, 0, 0);
      acc[0][1] = __builtin_amdgcn_mfma_f32_16x16x32_bf16(a0, b1, acc[0][1], 0, 0, 0);
      acc[1][0] = __builtin_amdgcn_mfma_f32_16x16x32_bf16(a1, b0, acc[1][0], 0, 0, 0);
      acc[1][1] = __builtin_amdgcn_mfma_f32_16x16x32_bf16(a1, b1, acc[1][1], 0, 0, 0);
    }
  }
  int rlo = (lane >> 4) << 2;
  int cl = lane & 15;
#pragma unroll
  for (int mi = 0; mi < 2; mi++) {
#pragma unroll
    for (int r = 0; r < 4; r++) {
      int row = (wr << 5) + mi * 16 + rlo + r;
      int grow = m0 + row;
      if (grow < c) {
        int slot = sSlot[row];
#pragma unroll
        for (int ni = 0; ni < 2; ni++) {
          int col = n0 + (wc << 5) + ni * 16 + cl;
          y[(size_t)slot * DMODEL + col] = acc[mi][ni][r];
        }
      }
    }
  }
}

// ---------------- final reduce over the 4 expert slots + scale ---------------------------
__global__ __launch_bounds__(256) void reducek(const float* __restrict__ y,
                                               const float* __restrict__ scale,
                                               float* __restrict__ out) {
  int i = blockIdx.x * 256 + (int)threadIdx.x;
  int t = i >> 8;
  int d = (i & 255) << 2;
  const float* yb = y + (size_t)t * 4 * DMODEL + d;
  f32x4 s = *(const f32x4*)(yb);
  s += *(const f32x4*)(yb + DMODEL);
  s += *(const f32x4*)(yb + 2 * DMODEL);
  s += *(const f32x4*)(yb + 3 * DMODEL);
  float sc = scale[0];
  s *= sc;
  *(f32x4*)(out + (size_t)t * DMODEL + d) = s;
}

extern "C" void kernel_launch(void* const* d_in, const int* in_sizes, int n_in,
                              void* d_out, int out_size, void* d_ws, size_t ws_size,
                              hipStream_t stream) {
  const float* x      = (const float*)d_in[0];
  const float* cen    = (const float*)d_in[1];
  const float* bias   = (const float*)d_in[2];
  const float* w_gate = (const float*)d_in[3];
  const float* w_up   = (const float*)d_in[4];
  const float* w_down = (const float*)d_in[5];
  const float* scale  = (const float*)d_in[6];
  float* out = (float*)d_out;

  char* ws = (char*)d_ws;
  unsigned short* xbf  = (unsigned short*)(ws);                 //  4 MB
  unsigned short* wgT  = (unsigned short*)(ws + 4194304);       // 16 MB  [E][H][D] bf16
  unsigned short* wuT  = (unsigned short*)(ws + 20971520);      // 16 MB
  unsigned short* wdT  = (unsigned short*)(ws + 37748736);      // 16 MB  [E][D][H] bf16
  unsigned short* hbuf = (unsigned short*)(ws + 54525952);      // 32 MB  [E][CAP][H] bf16
  float*          y    = (float*)(ws + 88080384);               // 32 MB  [T*4][D] f32
  int*            cnt  = (int*)(ws + 121634816);
  int*        listTok  = (int*)(ws + 121635072);
  float*     listGate  = (float*)(ws + 121766144);
  int*       listSlot  = (int*)(ws + 121897216);
  int*         selIdx  = (int*)(ws + 122028288);                // 32 KB
  float*      selGate  = (float*)(ws + 122061056);              // 32 KB

  tcast<<<dim3(16, 8, 16), 256, 0, stream>>>(w_gate, wgT, 1024, 512);
  tcast<<<dim3(16, 8, 16), 256, 0, stream>>>(w_up,   wuT, 1024, 512);
  tcast<<<dim3(8, 16, 16), 256, 0, stream>>>(w_down, wdT, 512, 1024);
  router<<<dim3(512), 256, 0, stream>>>(x, cen, bias, xbf, selIdx, selGate);
  buildlists<<<dim3(16), 256, 0, stream>>>(selIdx, selGate, cnt, listTok, listGate, listSlot);
  ffn1<<<dim3(8, 32, 16), 256, 0, stream>>>(xbf, wgT, wuT, cnt, listTok, listGate, hbuf);
  ffn2<<<dim3(16, 32, 16), 256, 0, stream>>>(hbuf, wdT, cnt, listSlot, y);
  reducek<<<dim3(2048), 256, 0, stream>>>(y, scale, out);
}